// Round 4
// baseline (4404.717 us; speedup 1.0000x reference)
//
#include <hip/hip_runtime.h>

typedef unsigned int u32;
typedef unsigned short u16;
typedef unsigned long long u64;
typedef float f32x4 __attribute__((ext_vector_type(4)));
typedef _Float16 f16x8 __attribute__((ext_vector_type(8)));

#define S_LEN 1024
#define NG 8      // groups (one per XCD, heuristically)
#define NM 32     // member blocks per group
#define GBAT 16   // batches per group
#define PSTR 20   // pred col stride (floats): 16B-aligned, bank-spread

__device__ __forceinline__ u16 f2h_bits(float f) {
  _Float16 h = (_Float16)f;
  return __builtin_bit_cast(u16, h);
}
__device__ __forceinline__ float h2f_bits(u16 b) {
  return (float)__builtin_bit_cast(_Float16, b);
}
__device__ __forceinline__ u32 pk2(float a, float b) {
  return (u32)f2h_bits(a) | ((u32)f2h_bits(b) << 16);
}
// u64 = two h words (lo: k, hi: k+1), each (seq<<16 | f16) -> packed f16 pair
__device__ __forceinline__ u32 pkh(u64 v) {
  return (u32)(v & 0xFFFFu) | (((u32)(v >> 32) & 0xFFFFu) << 16);
}

// Pre-arrange W into MFMA fragment-major order, fp16 (layout verified r2/r3).
// Per member m: frag[q(gate 0..3)][kc(0..15)][lane(0..63)] = uint4 (8 f16).
// Element (lane,e): k = kc*32 + (lane>>4)*8 + e ; gcol = q*512 + m*16 + (lane&15).
__global__ __launch_bounds__(256) void prep_frags(const float* __restrict__ Wi,
                                                  const float* __restrict__ Wh,
                                                  uint4* __restrict__ wf4) {
  const int blk = blockIdx.x;               // 0..63
  const int m = blk & 31;
  const float* __restrict__ W = (blk & 32) ? Wh : Wi;
  uint4* __restrict__ dst = wf4 + ((blk & 32) ? 131072 : 0) + m * 4096;
  for (int fi = threadIdx.x; fi < 4096; fi += 256) {
    const int lane = fi & 63;
    const int kc = (fi >> 6) & 15;
    const int q = fi >> 10;
    const int gq = lane >> 4, c = lane & 15;
    const int kb = kc * 32 + gq * 8;
    const int gcol = q * 512 + m * 16 + c;
    u32 wds[4];
#pragma unroll
    for (int pp = 0; pp < 4; ++pp) {
      u16 e0 = f2h_bits(W[(size_t)(kb + 2 * pp) * 2048 + gcol]);
      u16 e1 = f2h_bits(W[(size_t)(kb + 2 * pp + 1) * 2048 + gcol]);
      wds[pp] = (u32)e0 | ((u32)e1 << 16);
    }
    uint4 v; v.x = wds[0]; v.y = wds[1]; v.z = wds[2]; v.w = wds[3];
    dst[fi] = v;    // fi == (q*16+kc)*64+lane
  }
}

// Persistent LSTM. Group g = bid&7 owns batches [g*16,g*16+16);
// member m = bid>>3 owns h-indices [m*16,m*16+16).
// hbuf[2][128][512] u32, word = (seq16<<16)|f16(h). Sync = spin on embedded tags
// (relaxed agent atomics; per-location coherence makes tag reuse race-free).
// Raw s_barrier (not __syncthreads) so prefetch/publish vmem stays in flight.
__global__ __launch_bounds__(256) void lstm_main(
    const float* __restrict__ x,
    const uint4* __restrict__ wif4,
    u32* __restrict__ hbuf,
    const float* __restrict__ bvec,
    const float* __restrict__ Wd,
    const float* __restrict__ bd,
    float* __restrict__ out) {
  __shared__ __align__(16) uint4 sWi[4096];        // 64 KB
  __shared__ __align__(16) uint4 sWh[4096];        // 64 KB
  __shared__ __align__(16) float pred[16][PSTR * 16];  // 20 KB, col-major per tile

  const int tid = threadIdx.x;
  const int lane = tid & 63;
  const int wv = tid >> 6;
  const int g = blockIdx.x & 7;
  const int m = blockIdx.x >> 3;

  for (int i = tid; i < 4096; i += 256) {
    sWi[i] = wif4[m * 4096 + i];
    sWh[i] = wif4[131072 + m * 4096 + i];
  }

  const int bt = tid >> 4;          // batch within group (output row)
  const int hi_ = tid & 15;         // h-index within member slice (output col)
  const int gb = g * GBAT + bt;
  const int hidx = m * 16 + hi_;

  const float bi = bvec[hidx];
  const float bf_ = bvec[512 + hidx];
  const float bg = bvec[1024 + hidx];
  const float bo = bvec[1536 + hidx];
  float c_reg = 0.f;

  // per-lane A-fragment source coordinates (verified r2/r3)
  const int abt = lane & 15;        // batch row this lane supplies
  const int oct = lane >> 4;        // k-octet within kc
  const float* __restrict__ xrow = x + (size_t)(g * GBAT + abt) * (S_LEN * 512);
  const u32 hrow_off = ((u32)(g * GBAT + abt)) << 9;

  __syncthreads();   // weights ready (once; vmcnt drain here is fine)

  float4 xa[8], xb[8];
#pragma unroll
  for (int kk = 0; kk < 4; ++kk) {
    const int k0 = ((wv << 2) | kk) * 32 + oct * 8;
    xa[2 * kk]     = *reinterpret_cast<const float4*>(xrow + k0);
    xa[2 * kk + 1] = *reinterpret_cast<const float4*>(xrow + k0 + 4);
  }

  auto step = [&](int t, float4* cur, float4* nxt) {
    // ---- issue x(t+1) prefetch (into dead regs of nxt); clamp at end
    {
      int tn = t + 1; tn = (tn < S_LEN) ? tn : (S_LEN - 1);
      const float* xr = xrow + (size_t)tn * 512;
#pragma unroll
      for (int kk = 0; kk < 4; ++kk) {
        const int k0 = ((wv << 2) | kk) * 32 + oct * 8;
        nxt[2 * kk]     = *reinterpret_cast<const float4*>(xr + k0);
        nxt[2 * kk + 1] = *reinterpret_cast<const float4*>(xr + k0 + 4);
      }
    }

    // ---- x(t) @ Wi from prefetched regs (overlaps peers' publish propagation)
    f32x4 acc0 = {0.f, 0.f, 0.f, 0.f}, acc1 = acc0, acc2 = acc0, acc3 = acc0;
#pragma unroll
    for (int kk = 0; kk < 4; ++kk) {
      const int kc = (wv << 2) | kk;
      uint4 av;
      av.x = pk2(cur[2 * kk].x, cur[2 * kk].y);
      av.y = pk2(cur[2 * kk].z, cur[2 * kk].w);
      av.z = pk2(cur[2 * kk + 1].x, cur[2 * kk + 1].y);
      av.w = pk2(cur[2 * kk + 1].z, cur[2 * kk + 1].w);
      f16x8 af = __builtin_bit_cast(f16x8, av);
      acc0 = __builtin_amdgcn_mfma_f32_16x16x32_f16(af, __builtin_bit_cast(f16x8, sWi[(0 * 16 + kc) * 64 + lane]), acc0, 0, 0, 0);
      acc1 = __builtin_amdgcn_mfma_f32_16x16x32_f16(af, __builtin_bit_cast(f16x8, sWi[(1 * 16 + kc) * 64 + lane]), acc1, 0, 0, 0);
      acc2 = __builtin_amdgcn_mfma_f32_16x16x32_f16(af, __builtin_bit_cast(f16x8, sWi[(2 * 16 + kc) * 64 + lane]), acc2, 0, 0, 0);
      acc3 = __builtin_amdgcn_mfma_f32_16x16x32_f16(af, __builtin_bit_cast(f16x8, sWi[(3 * 16 + kc) * 64 + lane]), acc3, 0, 0, 0);
    }

    // ---- h(t) @ Wh : poll tagged words, then MFMA
    if (t > 0) {
      const u64* hp = reinterpret_cast<const u64*>(hbuf + (u32)(t & 1) * 65536u + hrow_off);
      const u32 want = (u32)t;
      const u64 wpat = ((u64)want << 16) | ((u64)want << 48);
      uint4 hv[4];
      for (;;) {
        u64 raw[4][4];
        u64 chk = 0;
#pragma unroll
        for (int kk = 0; kk < 4; ++kk) {
          const int base = (((wv << 2) | kk) << 4) | (oct << 2);
#pragma unroll
          for (int ee = 0; ee < 4; ++ee) {
            raw[kk][ee] = __hip_atomic_load(hp + base + ee, __ATOMIC_RELAXED,
                                            __HIP_MEMORY_SCOPE_AGENT);
            chk |= (raw[kk][ee] ^ wpat) & 0xFFFF0000FFFF0000ull;
          }
        }
        if (__all(chk == 0)) {
#pragma unroll
          for (int kk = 0; kk < 4; ++kk) {
            uint4 t4;
            t4.x = pkh(raw[kk][0]); t4.y = pkh(raw[kk][1]);
            t4.z = pkh(raw[kk][2]); t4.w = pkh(raw[kk][3]);
            hv[kk] = t4;
          }
          break;
        }
        __builtin_amdgcn_s_sleep(1);
      }
#pragma unroll
      for (int kk = 0; kk < 4; ++kk) {
        const int kc = (wv << 2) | kk;
        f16x8 hf = __builtin_bit_cast(f16x8, hv[kk]);
        acc0 = __builtin_amdgcn_mfma_f32_16x16x32_f16(hf, __builtin_bit_cast(f16x8, sWh[(0 * 16 + kc) * 64 + lane]), acc0, 0, 0, 0);
        acc1 = __builtin_amdgcn_mfma_f32_16x16x32_f16(hf, __builtin_bit_cast(f16x8, sWh[(1 * 16 + kc) * 64 + lane]), acc1, 0, 0, 0);
        acc2 = __builtin_amdgcn_mfma_f32_16x16x32_f16(hf, __builtin_bit_cast(f16x8, sWh[(2 * 16 + kc) * 64 + lane]), acc2, 0, 0, 0);
        acc3 = __builtin_amdgcn_mfma_f32_16x16x32_f16(hf, __builtin_bit_cast(f16x8, sWh[(3 * 16 + kc) * 64 + lane]), acc3, 0, 0, 0);
      }
    }

    // ---- K-partial tiles -> pred, col-major (rows contiguous): 4x ds_write_b128
    {
      const int cc = lane & 15;
      const int r0 = (lane >> 4) << 2;
      *reinterpret_cast<f32x4*>(&pred[wv * 4 + 0][PSTR * cc + r0]) = acc0;
      *reinterpret_cast<f32x4*>(&pred[wv * 4 + 1][PSTR * cc + r0]) = acc1;
      *reinterpret_cast<f32x4*>(&pred[wv * 4 + 2][PSTR * cc + r0]) = acc2;
      *reinterpret_cast<f32x4*>(&pred[wv * 4 + 3][PSTR * cc + r0]) = acc3;
    }
    // raw barrier: drain only LDS (lgkm), NOT vmem -> prefetch stays in flight
    asm volatile("s_waitcnt lgkmcnt(0)" ::: "memory");
    __builtin_amdgcn_s_barrier();
    __builtin_amdgcn_sched_barrier(0);

    // ---- gates; publish h(t+1) with embedded tag
    {
      float gi = bi, gf = bf_, gg = bg, go = bo;
#pragma unroll
      for (int w2 = 0; w2 < 4; ++w2) {
        gi += pred[w2 * 4 + 0][PSTR * hi_ + bt];
        gf += pred[w2 * 4 + 1][PSTR * hi_ + bt];
        gg += pred[w2 * 4 + 2][PSTR * hi_ + bt];
        go += pred[w2 * 4 + 3][PSTR * hi_ + bt];
      }
      const float si = 1.f / (1.f + __expf(-gi));
      const float sf = 1.f / (1.f + __expf(-gf));
      const float so = 1.f / (1.f + __expf(-go));
      c_reg = sf * c_reg + si * tanhf(gg);
      const float hv_ = so * tanhf(c_reg);
      const u32 word = ((u32)(t + 1) << 16) | (u32)f2h_bits(hv_);
      __hip_atomic_store(hbuf + (u32)((t + 1) & 1) * 65536u + (u32)gb * 512u + (u32)hidx,
                         word, __ATOMIC_RELAXED, __HIP_MEMORY_SCOPE_AGENT);
    }
    // raw barrier: protect pred reads (this step) vs pred writes (next step);
    // own reads are complete (consumed) before arrival, so no wait needed.
    __builtin_amdgcn_s_barrier();
    __builtin_amdgcn_sched_barrier(0);
  };

  for (int t = 0; t < S_LEN; t += 2) {
    step(t, xa, xb);
    step(t + 1, xb, xa);
  }

  // ---- Dense(1) on h(S): member 0 of each group, spin on tags == S_LEN (plane 0)
  if (m == 0) {
    const int btf = tid >> 4;
    const int part = tid & 15;
    const u64* hp = reinterpret_cast<const u64*>(hbuf + (((u32)(g * GBAT + btf)) << 9));
    const u32 want = (u32)S_LEN;
    const u64 wpat = ((u64)want << 16) | ((u64)want << 48);
    float acc = 0.f;
    for (;;) {
      u64 rawv[16];
      u64 chk = 0;
#pragma unroll
      for (int j2 = 0; j2 < 16; ++j2) {
        rawv[j2] = __hip_atomic_load(hp + part * 16 + j2, __ATOMIC_RELAXED,
                                     __HIP_MEMORY_SCOPE_AGENT);
        chk |= (rawv[j2] ^ wpat) & 0xFFFF0000FFFF0000ull;
      }
      if (__all(chk == 0)) {
        acc = 0.f;
#pragma unroll
        for (int j2 = 0; j2 < 16; ++j2) {
          const int k = part * 32 + 2 * j2;
          acc += h2f_bits((u16)(rawv[j2] & 0xFFFFu)) * Wd[k] +
                 h2f_bits((u16)((rawv[j2] >> 32) & 0xFFFFu)) * Wd[k + 1];
        }
        break;
      }
      __builtin_amdgcn_s_sleep(1);
    }
#pragma unroll
    for (int s = 1; s < 16; s <<= 1) acc += __shfl_xor(acc, s, 64);
    if (part == 0) out[g * GBAT + btf] = acc + bd[0];
  }
}

extern "C" void kernel_launch(void* const* d_in, const int* in_sizes, int n_in,
                              void* d_out, int out_size, void* d_ws, size_t ws_size,
                              hipStream_t stream) {
  const float* x = (const float*)d_in[0];
  const float* Wi = (const float*)d_in[1];
  const float* Wh = (const float*)d_in[2];
  const float* bv = (const float*)d_in[3];
  const float* Wd = (const float*)d_in[4];
  const float* bd = (const float*)d_in[5];
  float* out = (float*)d_out;

  // ws layout: [0, 4MB) W frags | [4MB, 4.5MB) h ping-pong (tagged words)
  char* ws = (char*)d_ws;
  uint4* wif4 = (uint4*)ws;
  u32* hbuf = (u32*)(ws + (4u << 20));

  hipLaunchKernelGGL(prep_frags, dim3(64), dim3(256), 0, stream, Wi, Wh, wif4);

  const float* kx = x;
  const uint4* kw = wif4;
  u32* kh = hbuf;
  const float* kbv = bv;
  const float* kwd = Wd;
  const float* kbd = bd;
  float* ko = out;
  void* args[] = {&kx, &kw, &kh, &kbv, &kwd, &kbd, &ko};
  hipLaunchCooperativeKernel(reinterpret_cast<void*>(lstm_main), dim3(NG * NM),
                             dim3(256), args, 0, stream);
}

// Round 6
// 4217.259 us; speedup vs baseline: 1.0445x; 1.0445x over previous
//
#include <hip/hip_runtime.h>

typedef unsigned int u32;
typedef unsigned short u16;
typedef unsigned long long u64;
typedef float f32x4 __attribute__((ext_vector_type(4)));
typedef _Float16 f16x8 __attribute__((ext_vector_type(8)));

#define S_LEN 1024
#define NG 8      // groups (one per XCD, heuristically)
#define NM 32     // member blocks per group
#define GBAT 16   // batches per group
#define PSTR 20   // pred col stride (floats): 16B-aligned, bank-spread

__device__ __forceinline__ u16 f2h_bits(float f) {
  _Float16 h = (_Float16)f;
  return __builtin_bit_cast(u16, h);
}
__device__ __forceinline__ float h2f_bits(u16 b) {
  return (float)__builtin_bit_cast(_Float16, b);
}
__device__ __forceinline__ u32 pk2(float a, float b) {
  return (u32)f2h_bits(a) | ((u32)f2h_bits(b) << 16);
}
// u64 = two h words (lo: k, hi: k+1), each (seq<<16 | f16) -> packed f16 pair
__device__ __forceinline__ u32 pkh(u64 v) {
  return (u32)(v & 0xFFFFu) | (((u32)(v >> 32) & 0xFFFFu) << 16);
}

// Pre-arrange W into MFMA fragment-major order, fp16 (layout verified r2-r4).
// Per member m: frag[q(gate 0..3)][kc(0..15)][lane(0..63)] = uint4 (8 f16).
// Element (lane,e): k = kc*32 + (lane>>4)*8 + e ; gcol = q*512 + m*16 + (lane&15).
__global__ __launch_bounds__(256) void prep_frags(const float* __restrict__ Wi,
                                                  const float* __restrict__ Wh,
                                                  uint4* __restrict__ wf4) {
  const int blk = blockIdx.x;               // 0..63
  const int m = blk & 31;
  const float* __restrict__ W = (blk & 32) ? Wh : Wi;
  uint4* __restrict__ dst = wf4 + ((blk & 32) ? 131072 : 0) + m * 4096;
  for (int fi = threadIdx.x; fi < 4096; fi += 256) {
    const int lane = fi & 63;
    const int kc = (fi >> 6) & 15;
    const int q = fi >> 10;
    const int gq = lane >> 4, c = lane & 15;
    const int kb = kc * 32 + gq * 8;
    const int gcol = q * 512 + m * 16 + c;
    u32 wds[4];
#pragma unroll
    for (int pp = 0; pp < 4; ++pp) {
      u16 e0 = f2h_bits(W[(size_t)(kb + 2 * pp) * 2048 + gcol]);
      u16 e1 = f2h_bits(W[(size_t)(kb + 2 * pp + 1) * 2048 + gcol]);
      wds[pp] = (u32)e0 | ((u32)e1 << 16);
    }
    uint4 v; v.x = wds[0]; v.y = wds[1]; v.z = wds[2]; v.w = wds[3];
    dst[fi] = v;    // fi == (q*16+kc)*64+lane
  }
}

// Persistent LSTM. Group g = bid&7 owns batches [g*16,g*16+16);
// member m = bid>>3 owns h-indices [m*16,m*16+16).
// hbuf[2][128][512] u32, word = (seq16<<16)|f16(h). Sync = spin on embedded tags
// (relaxed agent atomics; per-location coherence makes tag reuse race-free).
// KEY (r6): poll issues all 16 atomic loads with NO uses in between (pinned by
// sched_barrier), so they pipeline 16-deep in vmcnt -> ~1 LLC RTT per retry,
// instead of 16 serialized RTTs (the r3/r4 4.3us/step lockstep period).
__global__ __launch_bounds__(256) void lstm_main(
    const float* __restrict__ x,
    const uint4* __restrict__ wif4,
    u32* __restrict__ hbuf,
    const float* __restrict__ bvec,
    const float* __restrict__ Wd,
    const float* __restrict__ bd,
    float* __restrict__ out) {
  __shared__ __align__(16) uint4 sWi[4096];        // 64 KB
  __shared__ __align__(16) uint4 sWh[4096];        // 64 KB
  __shared__ __align__(16) float pred[16][PSTR * 16];  // 20 KB, col-major per tile

  const int tid = threadIdx.x;
  const int lane = tid & 63;
  const int wv = tid >> 6;
  const int g = blockIdx.x & 7;
  const int m = blockIdx.x >> 3;

  for (int i = tid; i < 4096; i += 256) {
    sWi[i] = wif4[m * 4096 + i];
    sWh[i] = wif4[131072 + m * 4096 + i];
  }

  const int bt = tid >> 4;          // batch within group (output row)
  const int hi_ = tid & 15;         // h-index within member slice (output col)
  const int gb = g * GBAT + bt;
  const int hidx = m * 16 + hi_;

  const float bi = bvec[hidx];
  const float bf_ = bvec[512 + hidx];
  const float bg = bvec[1024 + hidx];
  const float bo = bvec[1536 + hidx];
  float c_reg = 0.f;

  // per-lane A-fragment source coordinates (verified r2-r4)
  const int abt = lane & 15;        // batch row this lane supplies
  const int oct = lane >> 4;        // k-octet within kc
  const float* __restrict__ xrow = x + (size_t)(g * GBAT + abt) * (S_LEN * 512);
  const u32 hrow_off = ((u32)(g * GBAT + abt)) << 9;

  __syncthreads();   // weights ready (once; vmcnt drain here is fine)

  float4 xa[8], xb[8];
#pragma unroll
  for (int kk = 0; kk < 4; ++kk) {
    const int k0 = ((wv << 2) | kk) * 32 + oct * 8;
    xa[2 * kk]     = *reinterpret_cast<const float4*>(xrow + k0);
    xa[2 * kk + 1] = *reinterpret_cast<const float4*>(xrow + k0 + 4);
  }

  auto step = [&](int t, float4* cur, float4* nxt) {
    // ---- issue x(t+1) prefetch (into dead regs of nxt); clamp at end
    {
      int tn = t + 1; tn = (tn < S_LEN) ? tn : (S_LEN - 1);
      const float* xr = xrow + (size_t)tn * 512;
#pragma unroll
      for (int kk = 0; kk < 4; ++kk) {
        const int k0 = ((wv << 2) | kk) * 32 + oct * 8;
        nxt[2 * kk]     = *reinterpret_cast<const float4*>(xr + k0);
        nxt[2 * kk + 1] = *reinterpret_cast<const float4*>(xr + k0 + 4);
      }
    }

    // ---- x(t) @ Wi from prefetched regs (overlaps peers' publish propagation)
    f32x4 acc0 = {0.f, 0.f, 0.f, 0.f}, acc1 = acc0, acc2 = acc0, acc3 = acc0;
#pragma unroll
    for (int kk = 0; kk < 4; ++kk) {
      const int kc = (wv << 2) | kk;
      uint4 av;
      av.x = pk2(cur[2 * kk].x, cur[2 * kk].y);
      av.y = pk2(cur[2 * kk].z, cur[2 * kk].w);
      av.z = pk2(cur[2 * kk + 1].x, cur[2 * kk + 1].y);
      av.w = pk2(cur[2 * kk + 1].z, cur[2 * kk + 1].w);
      f16x8 af = __builtin_bit_cast(f16x8, av);
      acc0 = __builtin_amdgcn_mfma_f32_16x16x32_f16(af, __builtin_bit_cast(f16x8, sWi[(0 * 16 + kc) * 64 + lane]), acc0, 0, 0, 0);
      acc1 = __builtin_amdgcn_mfma_f32_16x16x32_f16(af, __builtin_bit_cast(f16x8, sWi[(1 * 16 + kc) * 64 + lane]), acc1, 0, 0, 0);
      acc2 = __builtin_amdgcn_mfma_f32_16x16x32_f16(af, __builtin_bit_cast(f16x8, sWi[(2 * 16 + kc) * 64 + lane]), acc2, 0, 0, 0);
      acc3 = __builtin_amdgcn_mfma_f32_16x16x32_f16(af, __builtin_bit_cast(f16x8, sWi[(3 * 16 + kc) * 64 + lane]), acc3, 0, 0, 0);
    }

    // ---- h(t) @ Wh : poll tagged words (batched loads), then MFMA
    if (t > 0) {
      const u64* hp = reinterpret_cast<const u64*>(hbuf + (u32)(t & 1) * 65536u + hrow_off);
      const u32 want = (u32)t;
      const u64 wpat = ((u64)want << 16) | ((u64)want << 48);
      u64 raw[4][4];
      for (;;) {
        // issue ALL 16 loads back-to-back; no uses in between
#pragma unroll
        for (int kk = 0; kk < 4; ++kk) {
          const int base = (((wv << 2) | kk) << 4) | (oct << 2);
#pragma unroll
          for (int ee = 0; ee < 4; ++ee)
            raw[kk][ee] = __hip_atomic_load(hp + base + ee, __ATOMIC_RELAXED,
                                            __HIP_MEMORY_SCOPE_AGENT);
        }
        __builtin_amdgcn_sched_barrier(0);  // keep checks below all loads
        u64 chk = 0;
#pragma unroll
        for (int kk = 0; kk < 4; ++kk)
#pragma unroll
          for (int ee = 0; ee < 4; ++ee)
            chk |= (raw[kk][ee] ^ wpat) & 0xFFFF0000FFFF0000ull;
        if (__all(chk == 0)) break;
        __builtin_amdgcn_s_sleep(1);
      }
      uint4 hv[4];
#pragma unroll
      for (int kk = 0; kk < 4; ++kk) {
        uint4 t4;
        t4.x = pkh(raw[kk][0]); t4.y = pkh(raw[kk][1]);
        t4.z = pkh(raw[kk][2]); t4.w = pkh(raw[kk][3]);
        hv[kk] = t4;
      }
#pragma unroll
      for (int kk = 0; kk < 4; ++kk) {
        const int kc = (wv << 2) | kk;
        f16x8 hf = __builtin_bit_cast(f16x8, hv[kk]);
        acc0 = __builtin_amdgcn_mfma_f32_16x16x32_f16(hf, __builtin_bit_cast(f16x8, sWh[(0 * 16 + kc) * 64 + lane]), acc0, 0, 0, 0);
        acc1 = __builtin_amdgcn_mfma_f32_16x16x32_f16(hf, __builtin_bit_cast(f16x8, sWh[(1 * 16 + kc) * 64 + lane]), acc1, 0, 0, 0);
        acc2 = __builtin_amdgcn_mfma_f32_16x16x32_f16(hf, __builtin_bit_cast(f16x8, sWh[(2 * 16 + kc) * 64 + lane]), acc2, 0, 0, 0);
        acc3 = __builtin_amdgcn_mfma_f32_16x16x32_f16(hf, __builtin_bit_cast(f16x8, sWh[(3 * 16 + kc) * 64 + lane]), acc3, 0, 0, 0);
      }
    }

    // ---- K-partial tiles -> pred, col-major (rows contiguous): 4x ds_write_b128
    {
      const int cc = lane & 15;
      const int r0 = (lane >> 4) << 2;
      *reinterpret_cast<f32x4*>(&pred[wv * 4 + 0][PSTR * cc + r0]) = acc0;
      *reinterpret_cast<f32x4*>(&pred[wv * 4 + 1][PSTR * cc + r0]) = acc1;
      *reinterpret_cast<f32x4*>(&pred[wv * 4 + 2][PSTR * cc + r0]) = acc2;
      *reinterpret_cast<f32x4*>(&pred[wv * 4 + 3][PSTR * cc + r0]) = acc3;
    }
    // raw barrier: drain only LDS (lgkm), NOT vmem -> prefetch stays in flight
    asm volatile("s_waitcnt lgkmcnt(0)" ::: "memory");
    __builtin_amdgcn_s_barrier();
    __builtin_amdgcn_sched_barrier(0);

    // ---- gates; publish h(t+1) with embedded tag
    {
      float gi = bi, gf = bf_, gg = bg, go = bo;
#pragma unroll
      for (int w2 = 0; w2 < 4; ++w2) {
        gi += pred[w2 * 4 + 0][PSTR * hi_ + bt];
        gf += pred[w2 * 4 + 1][PSTR * hi_ + bt];
        gg += pred[w2 * 4 + 2][PSTR * hi_ + bt];
        go += pred[w2 * 4 + 3][PSTR * hi_ + bt];
      }
      const float si = 1.f / (1.f + __expf(-gi));
      const float sf = 1.f / (1.f + __expf(-gf));
      const float so = 1.f / (1.f + __expf(-go));
      c_reg = sf * c_reg + si * tanhf(gg);
      const float hv_ = so * tanhf(c_reg);
      const u32 word = ((u32)(t + 1) << 16) | (u32)f2h_bits(hv_);
      __hip_atomic_store(hbuf + (u32)((t + 1) & 1) * 65536u + (u32)gb * 512u + (u32)hidx,
                         word, __ATOMIC_RELAXED, __HIP_MEMORY_SCOPE_AGENT);
    }
    // raw barrier: protect pred reads (this step) vs pred writes (next step);
    // own reads are complete (consumed) before arrival, so no wait needed.
    __builtin_amdgcn_s_barrier();
    __builtin_amdgcn_sched_barrier(0);
  };

  for (int t = 0; t < S_LEN; t += 2) {
    step(t, xa, xb);
    step(t + 1, xb, xa);
  }

  // ---- Dense(1) on h(S): member 0 of each group, spin on tags == S_LEN (plane 0)
  if (m == 0) {
    const int btf = tid >> 4;
    const int part = tid & 15;
    const u64* hp = reinterpret_cast<const u64*>(hbuf + (((u32)(g * GBAT + btf)) << 9));
    const u32 want = (u32)S_LEN;
    const u64 wpat = ((u64)want << 16) | ((u64)want << 48);
    u64 rawv[16];
    for (;;) {
#pragma unroll
      for (int j2 = 0; j2 < 16; ++j2)
        rawv[j2] = __hip_atomic_load(hp + part * 16 + j2, __ATOMIC_RELAXED,
                                     __HIP_MEMORY_SCOPE_AGENT);
      __builtin_amdgcn_sched_barrier(0);
      u64 chk = 0;
#pragma unroll
      for (int j2 = 0; j2 < 16; ++j2)
        chk |= (rawv[j2] ^ wpat) & 0xFFFF0000FFFF0000ull;
      if (__all(chk == 0)) break;
      __builtin_amdgcn_s_sleep(1);
    }
    float acc = 0.f;
#pragma unroll
    for (int j2 = 0; j2 < 16; ++j2) {
      const int k = part * 32 + 2 * j2;
      acc += h2f_bits((u16)(rawv[j2] & 0xFFFFu)) * Wd[k] +
             h2f_bits((u16)((rawv[j2] >> 32) & 0xFFFFu)) * Wd[k + 1];
    }
#pragma unroll
    for (int s = 1; s < 16; s <<= 1) acc += __shfl_xor(acc, s, 64);
    if (part == 0) out[g * GBAT + btf] = acc + bd[0];
  }
}

extern "C" void kernel_launch(void* const* d_in, const int* in_sizes, int n_in,
                              void* d_out, int out_size, void* d_ws, size_t ws_size,
                              hipStream_t stream) {
  const float* x = (const float*)d_in[0];
  const float* Wi = (const float*)d_in[1];
  const float* Wh = (const float*)d_in[2];
  const float* bv = (const float*)d_in[3];
  const float* Wd = (const float*)d_in[4];
  const float* bd = (const float*)d_in[5];
  float* out = (float*)d_out;

  // ws layout: [0, 4MB) W frags | [4MB, 4.5MB) h ping-pong (tagged words)
  char* ws = (char*)d_ws;
  uint4* wif4 = (uint4*)ws;
  u32* hbuf = (u32*)(ws + (4u << 20));

  hipLaunchKernelGGL(prep_frags, dim3(64), dim3(256), 0, stream, Wi, Wh, wif4);

  const float* kx = x;
  const uint4* kw = wif4;
  u32* kh = hbuf;
  const float* kbv = bv;
  const float* kwd = Wd;
  const float* kbd = bd;
  float* ko = out;
  void* args[] = {&kx, &kw, &kh, &kbv, &kwd, &kbd, &ko};
  hipLaunchCooperativeKernel(reinterpret_cast<void*>(lstm_main), dim3(NG * NM),
                             dim3(256), args, 0, stream);
}